// Round 1
// baseline (496.107 us; speedup 1.0000x reference)
//
#include <hip/hip_runtime.h>

// DCT_Layer: fixed 4x4 2D-DCT grouped conv, padding=2, then min(|out|, 8).
// x: (8, 3, 512, 512) fp32  ->  out: (8, 48, 513, 513) fp32
//
// v2 structure: separable DCT amortized over a 4-row output strip per thread.
//  - interior kernel: oh in [2,509], ow in [2,510]; NO bounds checks.
//    Each thread: load 7x4 patch (28 loads / 4 outputs), horizontal butterfly
//    once per row (7x), sliding vertical butterfly per output (16x), 64 stores.
//  - edge kernel: the 4,597 border pixels per (b,c) plane with predicated loads.
// Lanes consecutive in ow => all loads/stores dense-coalesced (256 B / wave instr).

#define IHW 512
#define OHW 513
#define PLANE ((size_t)OHW * (size_t)OHW)

__device__ __forceinline__ void bfly(float x0, float x1, float x2, float x3,
                                     float& y0, float& y1, float& y2, float& y3) {
    const float A1 = 0.6532814824381883f;   // sqrt(.5)*cos(pi/8)
    const float A2 = 0.2705980500730985f;   // sqrt(.5)*cos(3pi/8)
    float s03 = x0 + x3, d03 = x0 - x3;
    float s12 = x1 + x2, d12 = x1 - x2;
    y0 = 0.5f * (s03 + s12);
    y1 = A1 * d03 + A2 * d12;
    y2 = 0.5f * (s03 - s12);
    y3 = A2 * d03 - A1 * d12;
}

// Interior: 127 strips of 4 rows (oh0 = 2+4s, s=0..126 -> oh 2..509),
// ow in [2,510] (509 cols). All 7x4 input patches fully in-bounds.
__global__ __launch_bounds__(256) void dct_interior(const float* __restrict__ x,
                                                    float* __restrict__ out) {
    const int NT = 509 * 127;
    int t = blockIdx.x * 256 + threadIdx.x;
    if (t >= NT) return;
    int s = t / 509;                 // strip index 0..126
    int ow = 2 + (t - s * 509);      // 2..510, lane-consecutive
    int oh0 = 2 + 4 * s;             // 2..506
    int bc = blockIdx.y;             // b*3 + c, 0..23

    const float* __restrict__ xin =
        x + (size_t)bc * (IHW * IHW) + (size_t)(oh0 - 2) * IHW + (ow - 2);

    // Load 7 rows x 4 cols; horizontal transform each row immediately.
    float h[7][4];
#pragma unroll
    for (int i = 0; i < 7; ++i) {
        float p0 = xin[i * IHW + 0];
        float p1 = xin[i * IHW + 1];
        float p2 = xin[i * IHW + 2];
        float p3 = xin[i * IHW + 3];
        bfly(p0, p1, p2, p3, h[i][0], h[i][1], h[i][2], h[i][3]);
    }

    size_t obase = (size_t)bc * 16 * PLANE + (size_t)oh0 * OHW + (size_t)ow;
#pragma unroll
    for (int o = 0; o < 4; ++o) {
#pragma unroll
        for (int ll = 0; ll < 4; ++ll) {
            float v0, v1, v2, v3;   // kk = 0..3 -> plane kk*4+ll
            bfly(h[o][ll], h[o + 1][ll], h[o + 2][ll], h[o + 3][ll],
                 v0, v1, v2, v3);
            size_t a = obase + (size_t)o * OHW + (size_t)ll * PLANE;
            out[a]              = fminf(fabsf(v0), 8.0f);
            out[a + 4 * PLANE]  = fminf(fabsf(v1), 8.0f);
            out[a + 8 * PLANE]  = fminf(fabsf(v2), 8.0f);
            out[a + 12 * PLANE] = fminf(fabsf(v3), 8.0f);
        }
    }
}

// Edge: 4,597 pixels/plane = rows {0,1,510,511,512} full width, plus
// cols {0,1,511,512} for oh in [2,509]. Predicated per-pixel path.
__global__ __launch_bounds__(256) void dct_edge(const float* __restrict__ x,
                                                float* __restrict__ out) {
    const int NE = 4597;
    int e = blockIdx.x * 256 + threadIdx.x;
    if (e >= NE) return;
    int oh, ow;
    if (e < 1026) {                      // rows 0,1
        oh = (e >= 513) ? 1 : 0;
        ow = e - oh * 513;
    } else if (e < 2565) {               // rows 510,511,512
        int f = e - 1026;
        int r = f / 513;
        oh = 510 + r;
        ow = f - r * 513;
    } else {
        int f = e - 2565;
        if (f < 1016) {                  // cols 0,1; oh 2..509
            oh = 2 + (f >> 1);
            ow = f & 1;
        } else {                         // cols 511,512; oh 2..509
            f -= 1016;
            oh = 2 + (f >> 1);
            ow = 511 + (f & 1);
        }
    }
    int bc = blockIdx.y;
    const float* __restrict__ xin = x + (size_t)bc * (IHW * IHW);

    // 4x4 patch, zero outside [0,512)^2
    float p[4][4];
#pragma unroll
    for (int i = 0; i < 4; ++i) {
        int ih = oh - 2 + i;
        bool rv = ((unsigned)ih < (unsigned)IHW);
        const float* row = xin + ih * IHW;
#pragma unroll
        for (int j = 0; j < 4; ++j) {
            int iw = ow - 2 + j;
            bool ok = rv && ((unsigned)iw < (unsigned)IHW);
            p[i][j] = ok ? row[iw] : 0.0f;
        }
    }

    // horizontal per row, then vertical
    float h[4][4];
#pragma unroll
    for (int i = 0; i < 4; ++i)
        bfly(p[i][0], p[i][1], p[i][2], p[i][3], h[i][0], h[i][1], h[i][2], h[i][3]);

    size_t obase = (size_t)bc * 16 * PLANE + (size_t)oh * OHW + (size_t)ow;
#pragma unroll
    for (int ll = 0; ll < 4; ++ll) {
        float v0, v1, v2, v3;
        bfly(h[0][ll], h[1][ll], h[2][ll], h[3][ll], v0, v1, v2, v3);
        out[obase + (size_t)ll * PLANE]        = fminf(fabsf(v0), 8.0f);
        out[obase + (size_t)(4 + ll) * PLANE]  = fminf(fabsf(v1), 8.0f);
        out[obase + (size_t)(8 + ll) * PLANE]  = fminf(fabsf(v2), 8.0f);
        out[obase + (size_t)(12 + ll) * PLANE] = fminf(fabsf(v3), 8.0f);
    }
}

extern "C" void kernel_launch(void* const* d_in, const int* in_sizes, int n_in,
                              void* d_out, int out_size, void* d_ws, size_t ws_size,
                              hipStream_t stream) {
    const float* x = (const float*)d_in[0];
    float* out = (float*)d_out;

    dim3 gi((509 * 127 + 255) / 256, 24);   // 253 x 24
    hipLaunchKernelGGL(dct_interior, gi, dim3(256), 0, stream, x, out);

    dim3 ge((4597 + 255) / 256, 24);        // 18 x 24
    hipLaunchKernelGGL(dct_edge, ge, dim3(256), 0, stream, x, out);
}